// Round 2
// baseline (891.496 us; speedup 1.0000x reference)
//
#include <hip/hip_runtime.h>

#define NN 50000
#define NE 800000
#define H 128
#define K3H 384
#define NBLK 196   // ceil(NN/256)

typedef __bf16 bf16x8 __attribute__((ext_vector_type(8)));
typedef float f32x4 __attribute__((ext_vector_type(4)));

__device__ inline unsigned short f2bf(float f) {
    unsigned int u = __float_as_uint(f);
    u += 0x7FFFu + ((u >> 16) & 1u);   // round-to-nearest-even
    return (unsigned short)(u >> 16);
}
__device__ inline float bf2f(unsigned short u) {
    return __uint_as_float(((unsigned)u) << 16);
}

// W1t convert + zero count, fused
__global__ void prep(const float* __restrict__ W1, unsigned short* __restrict__ W1t,
                     int* __restrict__ count) {
    int o = blockIdx.x * 256 + threadIdx.x;
    if (o < K3H * H) {
        int n = o / K3H;
        int k = o - n * K3H;
        W1t[o] = f2bf(W1[k * H + n]);
    }
    int c = o - K3H * H;
    if (c >= 0 && c < NN) count[c] = 0;
}

__global__ void hist(const int* __restrict__ receivers, int* __restrict__ count) {
    int e = blockIdx.x * 256 + threadIdx.x;
    if (e < NE) atomicAdd(&count[receivers[e]], 1);
}

__global__ void scan_a(const int* __restrict__ count, int* __restrict__ offs,
                       int* __restrict__ bsum) {
    __shared__ int s[256];
    int t = threadIdx.x, i = blockIdx.x * 256 + t;
    int v = (i < NN) ? count[i] : 0;
    s[t] = v; __syncthreads();
    for (int off = 1; off < 256; off <<= 1) {
        int u = (t >= off) ? s[t - off] : 0;
        __syncthreads();
        s[t] += u; __syncthreads();
    }
    if (i < NN) offs[i] = s[t] - v;          // block-local exclusive
    if (t == 255) bsum[blockIdx.x] = s[255]; // block total
}

__global__ void scan_b(int* __restrict__ bsum) {
    __shared__ int s[256];
    int t = threadIdx.x;
    int v = (t < NBLK) ? bsum[t] : 0;
    s[t] = v; __syncthreads();
    for (int off = 1; off < 256; off <<= 1) {
        int u = (t >= off) ? s[t - off] : 0;
        __syncthreads();
        s[t] += u; __syncthreads();
    }
    if (t < NBLK) bsum[t] = s[t] - v;        // exclusive
}

__global__ void scan_c(int* __restrict__ offs, const int* __restrict__ bsum,
                       int* __restrict__ cursor) {
    int i = blockIdx.x * 256 + threadIdx.x;
    if (i < NN) {
        int o = offs[i] + bsum[i >> 8];
        offs[i] = o;
        cursor[i] = o;
    }
}

__global__ void scatter(const int* __restrict__ receivers, int* __restrict__ cursor,
                        int* __restrict__ edge_of) {
    int e = blockIdx.x * 256 + threadIdx.x;
    if (e < NE) {
        int pos = atomicAdd(&cursor[receivers[e]], 1);
        edge_of[pos] = e;
    }
}

__global__ void zero_aggr(float4* aggr) {
    int i = blockIdx.x * blockDim.x + threadIdx.x;
    aggr[i] = make_float4(0.f, 0.f, 0.f, 0.f);
}

// Per 128-edge tile (edges sorted by receiver): msg = relu(cat @ W1 + b1);
// segmented in-LDS column reduction, then one coalesced atomicAdd per (segment,col).
__global__ __launch_bounds__(256) void edge_gemm(
        const float* __restrict__ x,
        const int* __restrict__ senders,
        const int* __restrict__ receivers,
        const float* __restrict__ edge_feat,
        const unsigned short* __restrict__ W1t,
        const float* __restrict__ b1,
        const int* __restrict__ edge_of,
        float* __restrict__ aggr) {
    __shared__ short smem[18432];            // 36864 B
    short* const lds_a = smem;               // 128 x 72
    short* const lds_b = smem + 9216;        // 128 x 72
    short* const lds_c = smem;               // reused: 128 cols x 132 rows (33792 B)
    __shared__ int s_send[128];
    __shared__ int s_recv[128];
    __shared__ int s_eid[128];

    const int tid = threadIdx.x;
    const int e0 = blockIdx.x * 128;

    if (tid < 128) {
        int eid = edge_of[e0 + tid];
        s_eid[tid]  = eid;
        s_send[tid] = senders[eid];
        s_recv[tid] = receivers[eid];
    }
    __syncthreads();

    const int lane = tid & 63;
    const int wave = tid >> 6;
    const int wm = wave >> 1, wn = wave & 1;
    const int q = lane >> 4, l15 = lane & 15;

    f32x4 acc[4][4];
#pragma unroll
    for (int i = 0; i < 4; i++)
#pragma unroll
        for (int j = 0; j < 4; j++) acc[i][j] = (f32x4){0.f, 0.f, 0.f, 0.f};

    const int a_seg  = tid & 15;
    const int a_row0 = tid >> 4;
    const int b_seg  = tid & 7;
    const int b_row0 = tid >> 3;

    for (int c = 0; c < 6; ++c) {
        const int coloff = (c & 1) * 64;
        // --- stage A (gather + fp32->bf16) ---
#pragma unroll
        for (int p = 0; p < 8; ++p) {
            int row = a_row0 + p * 16;
            const float* src;
            if (c < 2)      src = x + (size_t)s_send[row] * H + coloff;
            else if (c < 4) src = x + (size_t)s_recv[row] * H + coloff;
            else            src = edge_feat + (size_t)s_eid[row] * H + coloff;
            float4 v = *(const float4*)(src + a_seg * 4);
            uint2 pk;
            pk.x = (unsigned)f2bf(v.x) | ((unsigned)f2bf(v.y) << 16);
            pk.y = (unsigned)f2bf(v.z) | ((unsigned)f2bf(v.w) << 16);
            *(uint2*)&lds_a[row * 72 + a_seg * 4] = pk;
        }
        // --- stage B ---
#pragma unroll
        for (int p = 0; p < 4; ++p) {
            int n = b_row0 + p * 32;
            uint4 v = *(const uint4*)(W1t + n * K3H + c * 64 + b_seg * 8);
            *(uint4*)&lds_b[n * 72 + b_seg * 8] = v;
        }
        __syncthreads();

        const short* pa = lds_a + (wm * 64 + l15) * 72 + q * 8;
        const short* pb = lds_b + (wn * 64 + l15) * 72 + q * 8;
#pragma unroll
        for (int ks = 0; ks < 2; ++ks) {
            bf16x8 af[4], bfr[4];
#pragma unroll
            for (int mi = 0; mi < 4; mi++)
                af[mi] = *(const bf16x8*)(const void*)(pa + mi * 16 * 72 + ks * 32);
#pragma unroll
            for (int ni = 0; ni < 4; ni++)
                bfr[ni] = *(const bf16x8*)(const void*)(pb + ni * 16 * 72 + ks * 32);
#pragma unroll
            for (int mi = 0; mi < 4; mi++)
#pragma unroll
                for (int ni = 0; ni < 4; ni++)
                    acc[mi][ni] = __builtin_amdgcn_mfma_f32_16x16x32_bf16(
                        af[mi], bfr[ni], acc[mi][ni], 0, 0, 0);
        }
        __syncthreads();
    }

    // --- epilogue: bias + relu, restage C as bf16 [col][row] (stride 132) ---
    float bias[4];
#pragma unroll
    for (int ni = 0; ni < 4; ni++) bias[ni] = b1[wn * 64 + ni * 16 + l15];

#pragma unroll
    for (int mi = 0; mi < 4; mi++) {
        int rbase = wm * 64 + mi * 16 + q * 4;   // C/D: row = quad*4 + reg
#pragma unroll
        for (int ni = 0; ni < 4; ni++) {
            int col = wn * 64 + ni * 16 + l15;
            float v0 = acc[mi][ni][0] + bias[ni]; v0 = v0 > 0.f ? v0 : 0.f;
            float v1 = acc[mi][ni][1] + bias[ni]; v1 = v1 > 0.f ? v1 : 0.f;
            float v2 = acc[mi][ni][2] + bias[ni]; v2 = v2 > 0.f ? v2 : 0.f;
            float v3 = acc[mi][ni][3] + bias[ni]; v3 = v3 > 0.f ? v3 : 0.f;
            uint2 pk;
            pk.x = (unsigned)f2bf(v0) | ((unsigned)f2bf(v1) << 16);
            pk.y = (unsigned)f2bf(v2) | ((unsigned)f2bf(v3) << 16);
            *(uint2*)&lds_c[col * 132 + rbase] = pk;
        }
    }
    __syncthreads();

    // --- segmented column reduction (rows sorted by receiver) ---
    {
        const int col  = tid & 127;
        const int half = tid >> 7;           // each half-warp-group does 64 rows
        const int r0 = half * 64;
        const short* pc = lds_c + col * 132;
        int prev = s_recv[r0];
        float sum = 0.f;
#pragma unroll 8
        for (int row = r0; row < r0 + 64; row += 2) {
            unsigned pk = *(const unsigned*)(pc + row);
            int rc0 = s_recv[row];
            int rc1 = s_recv[row + 1];
            if (rc0 != prev) { atomicAdd(&aggr[(size_t)prev * H + col], sum); sum = 0.f; prev = rc0; }
            sum += bf2f((unsigned short)(pk & 0xFFFFu));
            if (rc1 != prev) { atomicAdd(&aggr[(size_t)prev * H + col], sum); sum = 0.f; prev = rc1; }
            sum += bf2f((unsigned short)(pk >> 16));
        }
        atomicAdd(&aggr[(size_t)prev * H + col], sum);
    }
}

// h = aggr + x; out = layernorm(h)*gamma + beta. One wave per node row.
__global__ void residual_ln(const float* __restrict__ aggr, const float* __restrict__ x,
                            const float* __restrict__ gamma, const float* __restrict__ beta,
                            float* __restrict__ out) {
    int node = blockIdx.x * 4 + (threadIdx.x >> 6);
    int lane = threadIdx.x & 63;
    size_t off = (size_t)node * H + lane * 2;
    float2 a  = *(const float2*)(aggr + off);
    float2 xv = *(const float2*)(x + off);
    float h0 = a.x + xv.x, h1 = a.y + xv.y;
    float s = h0 + h1, sq = h0 * h0 + h1 * h1;
#pragma unroll
    for (int o = 32; o > 0; o >>= 1) {
        s  += __shfl_xor(s, o);
        sq += __shfl_xor(sq, o);
    }
    float mu  = s * (1.f / 128.f);
    float var = sq * (1.f / 128.f) - mu * mu;
    float rstd = rsqrtf(var + 1e-5f);
    float2 o2;
    o2.x = gamma[lane * 2]     * (h0 - mu) * rstd + beta[lane * 2];
    o2.y = gamma[lane * 2 + 1] * (h1 - mu) * rstd + beta[lane * 2 + 1];
    *(float2*)(out + off) = o2;
}

extern "C" void kernel_launch(void* const* d_in, const int* in_sizes, int n_in,
                              void* d_out, int out_size, void* d_ws, size_t ws_size,
                              hipStream_t stream) {
    const float* x         = (const float*)d_in[0];
    const int*   senders   = (const int*)d_in[1];
    const int*   receivers = (const int*)d_in[2];
    const float* edge_feat = (const float*)d_in[3];
    const float* W1        = (const float*)d_in[4];
    const float* b1        = (const float*)d_in[5];
    const float* gamma     = (const float*)d_in[6];
    const float* beta      = (const float*)d_in[7];
    float* out = (float*)d_out;

    char* ws = (char*)d_ws;
    float*          aggr    = (float*)(ws);                       // 25,600,000 B
    unsigned short* W1t     = (unsigned short*)(ws + 25600000);   //     98,304 B
    int*            count   = (int*)(ws + 25698304);              //    200,000 B
    int*            offs    = (int*)(ws + 25898304);              //    200,000 B
    int*            cursor  = (int*)(ws + 26098304);              //    200,000 B
    int*            bsum    = (int*)(ws + 26298304);              //      1,024 B
    int*            edge_of = (int*)(ws + 26299328);              //  3,200,000 B  (total ~29.5 MB)

    prep<<<388, 256, 0, stream>>>(W1, W1t, count);
    hist<<<NE / 256, 256, 0, stream>>>(receivers, count);
    scan_a<<<NBLK, 256, 0, stream>>>(count, offs, bsum);
    scan_b<<<1, 256, 0, stream>>>(bsum);
    scan_c<<<NBLK, 256, 0, stream>>>(offs, bsum, cursor);
    scatter<<<NE / 256, 256, 0, stream>>>(receivers, cursor, edge_of);
    zero_aggr<<<NN * H / 4 / 256, 256, 0, stream>>>((float4*)aggr);
    edge_gemm<<<NE / 128, 256, 0, stream>>>(x, senders, receivers, edge_feat, W1t, b1,
                                            edge_of, aggr);
    residual_ln<<<NN / 4, 256, 0, stream>>>(aggr, x, gamma, beta, out);
}